// Round 2
// baseline (22092.828 us; speedup 1.0000x reference)
//
#include <hip/hip_runtime.h>
#include <cstdint>
#include <cstddef>

// ---------------------------------------------------------------------------
// TransformerCoupledDecoder on MI355X (gfx950).
// Round 2: runtime input-dtype detection (fp32 vs bf16 device buffers) since
// round-1 NaN is most consistent with fp32 bytes misread as bf16. All inputs
// are canonicalized to bf16 ws copies; d_out stores branch on the detected
// flag (bf16 vs fp32). Compute: bf16 MFMA GEMMs + fp32 residual stream.
// ---------------------------------------------------------------------------

static constexpr int Lnum = 6, D = 256, NH = 8, DH = 32, DFF = 2048;
static constexpr int Qn = 300, Bn = 64, Sn = 1200;
static constexpr int NOBJ = 81, NVERB = 117, WDIM = 300;
static constexpr int TQ = Qn * Bn;   // 19200
static constexpr int TS = Sn * Bn;   // 76800
static constexpr long IOFF = 0;
static constexpr long VOFF = (long)Lnum * TQ * D;                 // 29,491,200
static constexpr long OOFF = VOFF + (long)Lnum * Bn * Qn * NVERB; // 42,969,600

typedef __attribute__((ext_vector_type(8))) short bf8;   // 8 x bf16 (4 VGPR)
typedef __attribute__((ext_vector_type(4))) float f4;    // MFMA acc

__device__ __forceinline__ float b2f(unsigned short u) {
  union { unsigned int i; float f; } x; x.i = ((unsigned int)u) << 16; return x.f;
}
__device__ __forceinline__ unsigned short f2b(float f) {
  union { float f; unsigned int i; } x; x.f = f;
  unsigned int r = (x.i + 0x7fffu + ((x.i >> 16) & 1u)) >> 16;  // RTNE
  return (unsigned short)r;
}
__device__ __forceinline__ float blo(unsigned int u) {
  union { unsigned int i; float f; } x; x.i = u << 16; return x.f;
}
__device__ __forceinline__ float bhi(unsigned int u) {
  union { unsigned int i; float f; } x; x.i = u & 0xffff0000u; return x.f;
}

// ---------------- dtype detection + input canonicalization -----------------
// probe points at an all-ones parameter (vnorm_s). fp32 one = 0x3F800000;
// two bf16 ones = 0x3F803F80.
__global__ void k_detect(const void* __restrict__ probe, int* __restrict__ flagp) {
  flagp[0] = (*(const unsigned int*)probe == 0x3F803F80u) ? 1 : 0;
}

// src (fp32 or bf16 per flag) -> bf16 dst
__global__ __launch_bounds__(256) void k_cvtin(
    const void* __restrict__ src, unsigned short* __restrict__ dst, int n,
    const int* __restrict__ flagp)
{
  const int i = blockIdx.x * 256 + threadIdx.x;
  if (i >= n) return;
  if (flagp[0]) dst[i] = ((const unsigned short*)src)[i];
  else          dst[i] = f2b(((const float*)src)[i]);
}

// tgt -> fp32 + bf16
__global__ __launch_bounds__(256) void k_cvt(
    const void* __restrict__ in, float* __restrict__ of,
    unsigned short* __restrict__ ob, const int* __restrict__ flagp)
{
  const size_t i = (size_t)blockIdx.x * 256 + threadIdx.x;
  if (flagp[0]) {
    const unsigned short u = ((const unsigned short*)in)[i];
    of[i] = b2f(u); ob[i] = u;
  } else {
    const float v = ((const float*)in)[i];
    of[i] = v; ob[i] = f2b(v);
  }
}

// memq = bf16(mem + pos), dual-dtype inputs
__global__ __launch_bounds__(256) void k_addin(
    const void* __restrict__ a, const void* __restrict__ b,
    unsigned short* __restrict__ c, const int* __restrict__ flagp)
{
  const size_t i = (size_t)blockIdx.x * 256 + threadIdx.x;
  float v;
  if (flagp[0]) v = b2f(((const unsigned short*)a)[i]) + b2f(((const unsigned short*)b)[i]);
  else          v = ((const float*)a)[i] + ((const float*)b)[i];
  c[i] = f2b(v);
}

// ---------------------------------------------------------------------------
// Generic MFMA GEMM: C[M,N] = act(A[M,K] @ W[N,K]^T + bias)
// A,W bf16; acc fp32. Tile 64x64, BK=32, 4 waves. M%64==0, K%32==0.
// outF: fp32 [M,N]. outBv+oboff: element-offset store, bf16 unless
// (dmode && flag==0) -> fp32 (d_out in an fp32 dataset). scatter remaps
// row=q*64+b -> b*sB + q*sQ + col for the swapaxes outputs.
// ---------------------------------------------------------------------------
__global__ __launch_bounds__(256) void k_gemm(
    const unsigned short* __restrict__ A, int lda,
    const unsigned short* __restrict__ W, int ldw,
    const unsigned short* __restrict__ bias,
    int N, int K, int act,
    float* __restrict__ outF,
    void* __restrict__ outBv, size_t oboff, int scatter, int sB, int sQ,
    const int* __restrict__ flagp, int dmode)
{
  __shared__ __align__(16) unsigned short As[64][40];
  __shared__ __align__(16) unsigned short Ws[64][40];
  const int m0 = blockIdx.y * 64;
  const int n0 = blockIdx.x * 64;
  const int tid = threadIdx.x;
  const int wid = tid >> 6, lane = tid & 63;
  const int srow = tid >> 2;          // 0..63
  const int scol = (tid & 3) << 3;    // 0,8,16,24
  const size_t arow = (size_t)(m0 + srow) * lda + scol;
  const bool wvalid = (n0 + srow) < N;
  const size_t wrow = (size_t)(n0 + srow) * ldw + scol;
  const int obf = (outBv && dmode) ? flagp[0] : 1;

  f4 acc[4];
#pragma unroll
  for (int j = 0; j < 4; ++j) acc[j] = (f4){0.f, 0.f, 0.f, 0.f};

  for (int k0 = 0; k0 < K; k0 += 32) {
    __syncthreads();
    *(uint4*)&As[srow][scol] = *(const uint4*)(A + arow + k0);
    uint4 wv = make_uint4(0u, 0u, 0u, 0u);
    if (wvalid) wv = *(const uint4*)(W + wrow + k0);
    *(uint4*)&Ws[srow][scol] = wv;
    __syncthreads();
    const int fr = lane & 15, fk = (lane >> 4) << 3;
    const bf8 af = *(const bf8*)&As[wid * 16 + fr][fk];
    const bf8 b0 = *(const bf8*)&Ws[ 0 + fr][fk];
    const bf8 b1 = *(const bf8*)&Ws[16 + fr][fk];
    const bf8 b2 = *(const bf8*)&Ws[32 + fr][fk];
    const bf8 b3 = *(const bf8*)&Ws[48 + fr][fk];
    acc[0] = __builtin_amdgcn_mfma_f32_16x16x32_bf16(af, b0, acc[0], 0, 0, 0);
    acc[1] = __builtin_amdgcn_mfma_f32_16x16x32_bf16(af, b1, acc[1], 0, 0, 0);
    acc[2] = __builtin_amdgcn_mfma_f32_16x16x32_bf16(af, b2, acc[2], 0, 0, 0);
    acc[3] = __builtin_amdgcn_mfma_f32_16x16x32_bf16(af, b3, acc[3], 0, 0, 0);
  }

  const int rbase = m0 + wid * 16 + ((lane >> 4) << 2);
  const int cbase = n0 + (lane & 15);
#pragma unroll
  for (int j = 0; j < 4; ++j) {
    const int col = cbase + j * 16;
    if (col < N) {
      const float bv = bias ? b2f(bias[col]) : 0.f;
#pragma unroll
      for (int r = 0; r < 4; ++r) {
        const int row = rbase + r;
        float v = acc[j][r] + bv;
        if (act == 1) v = fmaxf(v, 0.f);
        else if (act == 2) v = 1.f / (1.f + __expf(-v));
        if (outF) outF[(size_t)row * N + col] = v;
        if (outBv) {
          const size_t o = scatter
              ? ((size_t)(row & 63) * sB + (size_t)(row >> 6) * sQ + col)
              : ((size_t)row * N + col);
          if (obf) ((unsigned short*)outBv)[oboff + o] = f2b(v);
          else     ((float*)outBv)[oboff + o] = v;
        }
      }
    }
  }
}

// ---------------------------------------------------------------------------
// Flash-style attention, vector version. One wave per (b,h,q); 4 waves/block.
// q/k/v bf16, token stride ldq/ldk/ldv; head h at column h*32.
// ---------------------------------------------------------------------------
__global__ __launch_bounds__(256) void k_attn(
    const unsigned short* __restrict__ qb, int ldq,
    const unsigned short* __restrict__ kb, int ldk,
    const unsigned short* __restrict__ vb, int ldv,
    unsigned short* __restrict__ outp, int Lk)
{
  __shared__ float red[4][64][33];
  const int wid = threadIdx.x >> 6, lane = threadIdx.x & 63;
  const int g = blockIdx.x * 4 + wid;
  const int b = g / (NH * Qn);
  const int rem = g - b * (NH * Qn);
  const int h = rem / Qn;
  const int q = rem - h * Qn;

  const unsigned short* qp = qb + (size_t)(q * Bn + b) * ldq + h * DH;
  float qv[32];
#pragma unroll
  for (int c = 0; c < 4; ++c) {
    uint4 u = *(const uint4*)(qp + c * 8);
    qv[c*8+0] = blo(u.x); qv[c*8+1] = bhi(u.x);
    qv[c*8+2] = blo(u.y); qv[c*8+3] = bhi(u.y);
    qv[c*8+4] = blo(u.z); qv[c*8+5] = bhi(u.z);
    qv[c*8+6] = blo(u.w); qv[c*8+7] = bhi(u.w);
  }
  float o[32];
#pragma unroll
  for (int d = 0; d < 32; ++d) o[d] = 0.f;
  float m = -INFINITY, l = 0.f;

  for (int k = lane; k < Lk; k += 64) {
    const size_t roff = (size_t)(k * Bn + b);
    const unsigned short* kp = kb + roff * ldk + h * DH;
    float s = 0.f;
#pragma unroll
    for (int c = 0; c < 4; ++c) {
      uint4 u = *(const uint4*)(kp + c * 8);
      s += qv[c*8+0]*blo(u.x) + qv[c*8+1]*bhi(u.x)
         + qv[c*8+2]*blo(u.y) + qv[c*8+3]*bhi(u.y)
         + qv[c*8+4]*blo(u.z) + qv[c*8+5]*bhi(u.z)
         + qv[c*8+6]*blo(u.w) + qv[c*8+7]*bhi(u.w);
    }
    s *= 0.17677669529663687f;   // 1/sqrt(32)
    const float mn = fmaxf(m, s);
    const float corr = __expf(m - mn);   // m=-inf first iter -> 0
    const float p = __expf(s - mn);
    l = l * corr + p;
    const unsigned short* vp = vb + roff * ldv + h * DH;
#pragma unroll
    for (int c = 0; c < 4; ++c) {
      uint4 u = *(const uint4*)(vp + c * 8);
      o[c*8+0] = o[c*8+0]*corr + p*blo(u.x);
      o[c*8+1] = o[c*8+1]*corr + p*bhi(u.x);
      o[c*8+2] = o[c*8+2]*corr + p*blo(u.y);
      o[c*8+3] = o[c*8+3]*corr + p*bhi(u.y);
      o[c*8+4] = o[c*8+4]*corr + p*blo(u.z);
      o[c*8+5] = o[c*8+5]*corr + p*bhi(u.z);
      o[c*8+6] = o[c*8+6]*corr + p*blo(u.w);
      o[c*8+7] = o[c*8+7]*corr + p*bhi(u.w);
    }
    m = mn;
  }

  float M = m;
#pragma unroll
  for (int off = 32; off >= 1; off >>= 1) M = fmaxf(M, __shfl_xor(M, off));
  const float f = (m > -INFINITY) ? __expf(m - M) : 0.f;
  float lw = l * f;
#pragma unroll
  for (int off = 32; off >= 1; off >>= 1) lw += __shfl_xor(lw, off);
#pragma unroll
  for (int d = 0; d < 32; ++d) red[wid][lane][d] = o[d] * f;
  __syncthreads();
  const int c = lane & 31, half = lane >> 5;
  float s = 0.f;
#pragma unroll
  for (int i = 0; i < 32; ++i) s += red[wid][half * 32 + i][c];
  s += __shfl_xor(s, 32);
  if (lane < 32)
    outp[(size_t)(q * Bn + b) * D + h * DH + c] = f2b(s / lw);
}

// ---------------------------------------------------------------------------
// Fused (x + res) -> LayerNorm. Wave per token. outF fp32; outB1 bf16 ws;
// outB2v+o2off targets d_out (dtype per flag).
// ---------------------------------------------------------------------------
__global__ __launch_bounds__(256) void k_ln(
    const float* __restrict__ x, const float* __restrict__ res,
    const unsigned short* __restrict__ gs, const unsigned short* __restrict__ gb,
    float* __restrict__ outF, unsigned short* __restrict__ outB1,
    void* __restrict__ outB2v, size_t o2off, const int* __restrict__ flagp)
{
  const int wid = threadIdx.x >> 6, lane = threadIdx.x & 63;
  const size_t t = (size_t)blockIdx.x * 4 + wid;
  const int fl = outB2v ? flagp[0] : 1;
  const float* xp = x + t * D;
  float v[4];
#pragma unroll
  for (int j = 0; j < 4; ++j) {
    const int d = lane + j * 64;
    float u = xp[d];
    if (res) u += res[t * D + d];
    v[j] = u;
  }
  float s = v[0] + v[1] + v[2] + v[3];
  float ss = v[0]*v[0] + v[1]*v[1] + v[2]*v[2] + v[3]*v[3];
#pragma unroll
  for (int off = 32; off >= 1; off >>= 1) {
    s += __shfl_xor(s, off);
    ss += __shfl_xor(ss, off);
  }
  const float mean = s * (1.f / 256.f);
  const float var = ss * (1.f / 256.f) - mean * mean;
  const float rs = rsqrtf(var + 1e-5f);
#pragma unroll
  for (int j = 0; j < 4; ++j) {
    const int d = lane + j * 64;
    const float y = (v[j] - mean) * rs * b2f(gs[d]) + b2f(gb[d]);
    if (outF) outF[t * D + d] = y;
    if (outB1) outB1[t * D + d] = f2b(y);
    if (outB2v) {
      if (fl) ((unsigned short*)outB2v)[o2off + t * D + d] = f2b(y);
      else    ((float*)outB2v)[o2off + t * D + d] = y;
    }
  }
}

// -------------------------- elementwise helpers ----------------------------
__global__ __launch_bounds__(256) void k_addfb(
    const float* __restrict__ a, const unsigned short* __restrict__ b,
    unsigned short* __restrict__ c)
{
  const size_t i = (size_t)blockIdx.x * 256 + threadIdx.x;
  c[i] = f2b(a[i] + b2f(b[i]));
}
// out_aug = gate * sem + inter (all bf16 ins) -> fp32 + bf16
__global__ __launch_bounds__(256) void k_aug(
    const unsigned short* __restrict__ g, const unsigned short* __restrict__ sm,
    const unsigned short* __restrict__ it, float* __restrict__ of,
    unsigned short* __restrict__ ob)
{
  const size_t i = (size_t)blockIdx.x * 256 + threadIdx.x;
  const float v = b2f(g[i]) * b2f(sm[i]) + b2f(it[i]);
  of[i] = v;
  ob[i] = f2b(v);
}

// argmax over NOBJ=81 logits, first-max tie-break (matches np.argmax).
__global__ __launch_bounds__(256) void k_argmax(
    const float* __restrict__ logits, int* __restrict__ idx)
{
  const int wid = threadIdx.x >> 6, lane = threadIdx.x & 63;
  const size_t t = (size_t)blockIdx.x * 4 + wid;
  const float* p = logits + t * NOBJ;
  float bv = -INFINITY; int bi = 0;
  bv = p[lane < NOBJ ? lane : 0]; bi = lane < NOBJ ? lane : 0;
  if (lane >= NOBJ) { bv = p[0]; bi = 0; }
  if (lane + 64 < NOBJ) {
    const float v = p[lane + 64];
    if (v > bv) { bv = v; bi = lane + 64; }
  }
#pragma unroll
  for (int off = 32; off >= 1; off >>= 1) {
    const float ov = __shfl_xor(bv, off);
    const int oi = __shfl_xor(bi, off);
    if (ov > bv || (ov == bv && oi < bi)) { bv = ov; bi = oi; }
  }
  if (lane == 0) idx[t] = bi;
}

// cog[t][0..128) = co[idx[t]][0..117), zero-padded to K=128.
__global__ __launch_bounds__(256) void k_gather(
    const int* __restrict__ idx, const unsigned short* __restrict__ co,
    unsigned short* __restrict__ cog)
{
  const size_t n = (size_t)blockIdx.x * 256 + threadIdx.x;
  const int t = (int)(n >> 7), j = (int)(n & 127);
  cog[n] = (j < NVERB) ? co[(size_t)idx[t] * NVERB + j] : (unsigned short)0;
}

// -------------------------- semantic graph (tiny) --------------------------
__global__ __launch_bounds__(256) void k_semproj(
    const unsigned short* __restrict__ wemb, const unsigned short* __restrict__ sw,
    const unsigned short* __restrict__ sb, float* __restrict__ out)
{
  const int j = blockIdx.y;
  const int n = blockIdx.x * 256 + threadIdx.x;   // < 117*256
  const int mm = n >> 8, c = n & 255;
  const unsigned short* wr = sw + (size_t)(j * D + c) * WDIM;
  const unsigned short* xr = wemb + (size_t)mm * WDIM;
  float s = 0.f;
  for (int k = 0; k < WDIM; ++k) s += b2f(xr[k]) * b2f(wr[k]);
  out[(size_t)j * (NVERB * D) + n] = s + b2f(sb[j * D + c]);
}
__global__ __launch_bounds__(256) void k_semqk(
    const float* __restrict__ sq, const float* __restrict__ sk,
    float* __restrict__ sqk)
{
  const int n = blockIdx.x * 256 + threadIdx.x;
  if (n >= NVERB * NVERB) return;
  const int mm = n / NVERB, c = n - mm * NVERB;
  float s = 0.f;
  for (int k = 0; k < D; ++k) s += sq[mm * D + k] * sk[c * D + k];
  sqk[n] = s;
}
__global__ __launch_bounds__(256) void k_semfin(
    const float* __restrict__ sqk, const float* __restrict__ sv,
    const float* __restrict__ s3, unsigned short* __restrict__ semT)
{
  const int n = blockIdx.x * 256 + threadIdx.x;   // 256*128
  const int c = n >> 7, mm = n & 127;
  unsigned short r = 0;
  if (mm < NVERB) {
    float s = 0.f;
    for (int k = 0; k < NVERB; ++k) s += sqk[mm * NVERB + k] * sv[k * D + c];
    r = f2b(fmaxf(s, 0.f) + s3[mm * D + c]);
  }
  semT[c * 128 + mm] = r;
}

// ---------------------------------------------------------------------------
extern "C" void kernel_launch(void* const* d_in, const int* in_sizes, int n_in,
                              void* d_out, int out_size, void* d_ws, size_t ws_size,
                              hipStream_t stream)
{
  const void* tgt      = d_in[0];
  const void* mem      = d_in[1];
  const void* qpos     = d_in[2];
  const void* pos      = d_in[3];
  const void* sa_in_w  = d_in[4];
  const void* sa_in_b  = d_in[5];
  const void* sa_out_w = d_in[6];
  const void* sa_out_b = d_in[7];
  const void* ca_in_w  = d_in[8];
  const void* ca_in_b  = d_in[9];
  const void* ca_out_w = d_in[10];
  const void* ca_out_b = d_in[11];
  const void* ln_s     = d_in[12];
  const void* ln_b     = d_in[13];
  const void* ff1_w    = d_in[14];
  const void* ff1_b    = d_in[15];
  const void* ff2_w    = d_in[16];
  const void* ff2_b    = d_in[17];
  const void* sem_w    = d_in[18];
  const void* sem_b    = d_in[19];
  const void* gate_w   = d_in[20];
  const void* gate_b   = d_in[21];
  const void* vnorm_s  = d_in[22];
  const void* vnorm_b  = d_in[23];
  const void* fnorm_s  = d_in[24];
  const void* fnorm_b  = d_in[25];
  const void* obj_w    = d_in[26];
  const void* obj_b    = d_in[27];
  const void* verb_w   = d_in[28];
  const void* verb_b   = d_in[29];
  const void* wemb = d_in[30];
  const void* co   = d_in[31];
  if (in_sizes[30] == NOBJ * NVERB) { co = d_in[30]; wemb = d_in[31]; }
  (void)ws_size; (void)out_size; (void)n_in;

  // ----- workspace carving (deterministic; same every call) -----
  char* wp = (char*)d_ws;
  auto alloc = [&](size_t bytes) -> void* {
    void* p = (void*)wp;
    wp += (bytes + 255) & ~(size_t)255;
    return p;
  };
  int*   flagp   = (int*)alloc(256);
  float* out_f   = (float*)alloc((size_t)TQ * D * 4);
  float* x_f     = (float*)alloc((size_t)TQ * D * 4);
  float* t0_f    = (float*)alloc((size_t)TQ * D * 4);
  float* obj_f   = (float*)alloc((size_t)TQ * NOBJ * 4);
  int*   idx     = (int*)alloc((size_t)TQ * 4);
  unsigned short* out_bf   = (unsigned short*)alloc((size_t)TQ * D * 2);
  unsigned short* qk_bf    = (unsigned short*)alloc((size_t)TQ * D * 2);
  unsigned short* qk2_bf   = (unsigned short*)alloc((size_t)TQ * 512 * 2); // SA q|k; reused as CA q
  unsigned short* v_bf     = (unsigned short*)alloc((size_t)TQ * D * 2);
  unsigned short* attn_bf  = (unsigned short*)alloc((size_t)TQ * D * 2);
  unsigned short* x_bf     = (unsigned short*)alloc((size_t)TQ * D * 2);   // FF1 in; reused as vln
  unsigned short* inter_bf = (unsigned short*)alloc((size_t)TQ * D * 2);
  unsigned short* gate_bf  = (unsigned short*)alloc((size_t)TQ * D * 2);
  unsigned short* sem_bf   = (unsigned short*)alloc((size_t)TQ * D * 2);
  unsigned short* memq_bf  = (unsigned short*)alloc((size_t)TS * D * 2);
  unsigned short* mem_bf   = (unsigned short*)alloc((size_t)TS * D * 2);
  // union: {kca|vca} (2*TS*D) and ffh (TQ*DFF) are both 39,321,600 elems and
  // have disjoint lifetimes within a layer.
  unsigned short* uni      = (unsigned short*)alloc((size_t)2 * TS * D * 2);
  unsigned short* kca_bf   = uni;
  unsigned short* vca_bf   = uni + (size_t)TS * D;
  unsigned short* ffh_bf   = uni;
  unsigned short* cog_bf   = (unsigned short*)alloc((size_t)TQ * 128 * 2);
  unsigned short* semT_bf  = (unsigned short*)alloc((size_t)D * 128 * 2);
  float* semp_f = (float*)alloc((size_t)4 * NVERB * D * 4);   // sq|sk|sv|s3
  float* sqk_f  = (float*)alloc((size_t)NVERB * NVERB * 4);
  unsigned short* qca_bf = qk2_bf;   // alias (SA qk dead before CA q write)
  unsigned short* vln_bf = x_bf;     // alias (FF1 consumed x_bf already)
  unsigned short* dout = (unsigned short*)d_out;

  // ----- dtype detect + input canonicalization -----
  k_detect<<<1, 1, 0, stream>>>(vnorm_s, flagp);
  auto cvt = [&](const void* src, size_t n) -> unsigned short* {
    unsigned short* dst = (unsigned short*)alloc(n * 2);
    k_cvtin<<<(unsigned)((n + 255) / 256), 256, 0, stream>>>(src, dst, (int)n, flagp);
    return dst;
  };
  unsigned short* qpos_b  = cvt(qpos, (size_t)TQ * D);
  unsigned short* saw_b   = cvt(sa_in_w, (size_t)Lnum * 768 * D);
  unsigned short* sab_b   = cvt(sa_in_b, (size_t)Lnum * 768);
  unsigned short* saow_b  = cvt(sa_out_w, (size_t)Lnum * D * D);
  unsigned short* saob_b  = cvt(sa_out_b, (size_t)Lnum * D);
  unsigned short* caw_b   = cvt(ca_in_w, (size_t)Lnum * 768 * D);
  unsigned short* cab_b   = cvt(ca_in_b, (size_t)Lnum * 768);
  unsigned short* caow_b  = cvt(ca_out_w, (size_t)Lnum * D * D);
  unsigned short* caob_b  = cvt(ca_out_b, (size_t)Lnum * D);
  unsigned short* lns_b   = cvt(ln_s, (size_t)Lnum * 3 * D);
  unsigned short* lnb_b   = cvt(ln_b, (size_t)Lnum * 3 * D);
  unsigned short* ff1w_b  = cvt(ff1_w, (size_t)Lnum * DFF * D);
  unsigned short* ff1b_b  = cvt(ff1_b, (size_t)Lnum * DFF);
  unsigned short* ff2w_b  = cvt(ff2_w, (size_t)Lnum * D * DFF);
  unsigned short* ff2b_b  = cvt(ff2_b, (size_t)Lnum * D);
  unsigned short* semw_b  = cvt(sem_w, (size_t)4 * D * WDIM);
  unsigned short* semb_b  = cvt(sem_b, (size_t)4 * D);
  unsigned short* gatew_b = cvt(gate_w, (size_t)D * D);
  unsigned short* gateb_b = cvt(gate_b, (size_t)D);
  unsigned short* vns_b   = cvt(vnorm_s, (size_t)D);
  unsigned short* vnb_b   = cvt(vnorm_b, (size_t)D);
  unsigned short* fns_b   = cvt(fnorm_s, (size_t)D);
  unsigned short* fnb_b   = cvt(fnorm_b, (size_t)D);
  unsigned short* objw_b  = cvt(obj_w, (size_t)NOBJ * D);
  unsigned short* objb_b  = cvt(obj_b, (size_t)NOBJ);
  unsigned short* verbw_b = cvt(verb_w, (size_t)NVERB * D);
  unsigned short* verbb_b = cvt(verb_b, (size_t)NVERB);
  unsigned short* co_b    = cvt(co, (size_t)NOBJ * NVERB);
  unsigned short* wemb_b  = cvt(wemb, (size_t)NVERB * WDIM);
  k_cvtin<<<(TS * D + 255) / 256, 256, 0, stream>>>(mem, mem_bf, TS * D, flagp);

  auto gemm = [&](const void* A, int lda, const void* W, int ldw,
                  const void* bias, int M, int N, int K, int act,
                  void* outF, void* outBv, size_t oboff, int scatter,
                  int sB, int sQ, int dmode) {
    dim3 grid((N + 63) / 64, M / 64);
    k_gemm<<<grid, dim3(256), 0, stream>>>(
        (const unsigned short*)A, lda, (const unsigned short*)W, ldw,
        (const unsigned short*)bias, N, K, act,
        (float*)outF, outBv, oboff, scatter, sB, sQ, flagp, dmode);
  };

  // ----- pre-loop -----
  k_cvt<<<TQ * D / 256, 256, 0, stream>>>(tgt, out_f, out_bf, flagp);
  k_addin<<<TS * D / 256, 256, 0, stream>>>(mem, pos, memq_bf, flagp);
  k_semproj<<<dim3(NVERB, 4), 256, 0, stream>>>(wemb_b, semw_b, semb_b, semp_f);
  k_semqk<<<(NVERB * NVERB + 255) / 256, 256, 0, stream>>>(
      semp_f, semp_f + NVERB * D, sqk_f);
  k_semfin<<<(D * 128) / 256, 256, 0, stream>>>(
      sqk_f, semp_f + 2 * NVERB * D, semp_f + 3 * NVERB * D, semT_bf);

  const int attn_grid = Bn * NH * Qn / 4;   // 38400

  for (int i = 0; i < Lnum; ++i) {
    const unsigned short* saw = saw_b + (size_t)i * 768 * D;
    const unsigned short* sab = sab_b + (size_t)i * 768;
    const unsigned short* caw = caw_b + (size_t)i * 768 * D;
    const unsigned short* cab = cab_b + (size_t)i * 768;

    // -------- self-attention --------
    k_addfb<<<TQ * D / 256, 256, 0, stream>>>(out_f, qpos_b, qk_bf);
    gemm(qk_bf, D, saw, D, sab, TQ, 512, D, 0, nullptr, qk2_bf, 0, 0, 0, 0, 0);
    gemm(out_bf, D, saw + (size_t)512 * D, D, sab + 512, TQ, D, D, 0,
         nullptr, v_bf, 0, 0, 0, 0, 0);
    k_attn<<<attn_grid, 256, 0, stream>>>(qk2_bf, 512, qk2_bf + 256, 512,
                                          v_bf, D, attn_bf, Qn);
    gemm(attn_bf, D, saow_b + (size_t)i * D * D, D, saob_b + (size_t)i * D,
         TQ, D, D, 0, t0_f, nullptr, 0, 0, 0, 0, 0);
    k_ln<<<TQ / 4, 256, 0, stream>>>(out_f, t0_f, lns_b + (size_t)(i*3+0)*D,
                                     lnb_b + (size_t)(i*3+0)*D,
                                     x_f, (unsigned short*)nullptr,
                                     nullptr, 0, flagp);

    // -------- cross-attention --------
    k_addfb<<<TQ * D / 256, 256, 0, stream>>>(x_f, qpos_b, qk_bf);
    gemm(qk_bf, D, caw, D, cab, TQ, D, D, 0, nullptr, qca_bf, 0, 0, 0, 0, 0);
    gemm(memq_bf, D, caw + (size_t)256 * D, D, cab + 256, TS, D, D, 0,
         nullptr, kca_bf, 0, 0, 0, 0, 0);
    gemm(mem_bf, D, caw + (size_t)512 * D, D, cab + 512, TS, D, D, 0,
         nullptr, vca_bf, 0, 0, 0, 0, 0);
    k_attn<<<attn_grid, 256, 0, stream>>>(qca_bf, D, kca_bf, D, vca_bf, D,
                                          attn_bf, Sn);
    gemm(attn_bf, D, caow_b + (size_t)i * D * D, D, caob_b + (size_t)i * D,
         TQ, D, D, 0, t0_f, nullptr, 0, 0, 0, 0, 0);
    k_ln<<<TQ / 4, 256, 0, stream>>>(x_f, t0_f, lns_b + (size_t)(i*3+1)*D,
                                     lnb_b + (size_t)(i*3+1)*D,
                                     x_f, x_bf, nullptr, 0, flagp);

    // -------- feed-forward --------
    gemm(x_bf, D, ff1w_b + (size_t)i * DFF * D, D, ff1b_b + (size_t)i * DFF,
         TQ, DFF, D, 1, nullptr, ffh_bf, 0, 0, 0, 0, 0);
    gemm(ffh_bf, DFF, ff2w_b + (size_t)i * D * DFF, DFF, ff2b_b + (size_t)i * D,
         TQ, D, DFF, 0, t0_f, nullptr, 0, 0, 0, 0, 0);
    k_ln<<<TQ / 4, 256, 0, stream>>>(x_f, t0_f, lns_b + (size_t)(i*3+2)*D,
                                     lnb_b + (size_t)(i*3+2)*D,
                                     out_f, (unsigned short*)nullptr,
                                     nullptr, 0, flagp);

    // -------- heads + semantic augmentation --------
    k_ln<<<TQ / 4, 256, 0, stream>>>(out_f, (const float*)nullptr, fns_b,
                                     fnb_b, (float*)nullptr, inter_bf,
                                     (i < 5) ? d_out : nullptr,
                                     IOFF + (size_t)i * TQ * D, flagp);
    gemm(inter_bf, D, objw_b, D, objb_b, TQ, NOBJ, D, 0, obj_f,
         d_out, OOFF + (size_t)i * Bn * Qn * NOBJ, 1, Qn * NOBJ, NOBJ, 1);
    k_argmax<<<TQ / 4, 256, 0, stream>>>(obj_f, idx);
    k_gather<<<TQ * 128 / 256, 256, 0, stream>>>(idx, co_b, cog_bf);
    gemm(cog_bf, 128, semT_bf, 128, nullptr, TQ, D, 128, 0, nullptr, sem_bf,
         0, 0, 0, 0, 0);
    gemm(inter_bf, D, gatew_b, D, gateb_b, TQ, D, D, 2, nullptr, gate_bf,
         0, 0, 0, 0, 0);
    k_aug<<<TQ * D / 256, 256, 0, stream>>>(gate_bf, sem_bf, inter_bf, out_f,
                                            out_bf);
    k_ln<<<TQ / 4, 256, 0, stream>>>(out_f, (const float*)nullptr, vns_b,
                                     vnb_b, (float*)nullptr, vln_bf,
                                     nullptr, 0, flagp);
    gemm(vln_bf, D, verbw_b, D, verbb_b, TQ, NVERB, D, 0, nullptr,
         d_out, VOFF + (size_t)i * Bn * Qn * NVERB, 1, Qn * NVERB, NVERB, 1);
  }

  // inters[-1] = LN(out_aug_5, fnorm)
  k_ln<<<TQ / 4, 256, 0, stream>>>(out_f, (const float*)nullptr, fns_b,
                                   fnb_b, (float*)nullptr,
                                   (unsigned short*)nullptr,
                                   d_out, IOFF + (size_t)5 * TQ * D, flagp);
  (void)dout;
}

// Round 3
// 4539.456 us; speedup vs baseline: 4.8668x; 4.8668x over previous
//
#include <hip/hip_runtime.h>
#include <cstdint>
#include <cstddef>

// ---------------------------------------------------------------------------
// TransformerCoupledDecoder on MI355X (gfx950).
// Round 3: replace vector flash-attention (MfmaUtil=0, 2.6ms/dispatch) with
// MFMA flash-attention (block = (b,h,qtile64), online softmax, LDS-staged
// K / V^T, P via wave-private LDS strip). Rest identical to passing round 2.
// ---------------------------------------------------------------------------

static constexpr int Lnum = 6, D = 256, NH = 8, DH = 32, DFF = 2048;
static constexpr int Qn = 300, Bn = 64, Sn = 1200;
static constexpr int NOBJ = 81, NVERB = 117, WDIM = 300;
static constexpr int TQ = Qn * Bn;   // 19200
static constexpr int TS = Sn * Bn;   // 76800
static constexpr long IOFF = 0;
static constexpr long VOFF = (long)Lnum * TQ * D;                 // 29,491,200
static constexpr long OOFF = VOFF + (long)Lnum * Bn * Qn * NVERB; // 42,969,600

typedef __attribute__((ext_vector_type(8))) short bf8;   // 8 x bf16 (4 VGPR)
typedef __attribute__((ext_vector_type(4))) float f4;    // MFMA acc

__device__ __forceinline__ float b2f(unsigned short u) {
  union { unsigned int i; float f; } x; x.i = ((unsigned int)u) << 16; return x.f;
}
__device__ __forceinline__ unsigned short f2b(float f) {
  union { float f; unsigned int i; } x; x.f = f;
  unsigned int r = (x.i + 0x7fffu + ((x.i >> 16) & 1u)) >> 16;  // RTNE
  return (unsigned short)r;
}
__device__ __forceinline__ float blo(unsigned int u) {
  union { unsigned int i; float f; } x; x.i = u << 16; return x.f;
}
__device__ __forceinline__ float bhi(unsigned int u) {
  union { unsigned int i; float f; } x; x.i = u & 0xffff0000u; return x.f;
}

// ---------------- dtype detection + input canonicalization -----------------
__global__ void k_detect(const void* __restrict__ probe, int* __restrict__ flagp) {
  flagp[0] = (*(const unsigned int*)probe == 0x3F803F80u) ? 1 : 0;
}

__global__ __launch_bounds__(256) void k_cvtin(
    const void* __restrict__ src, unsigned short* __restrict__ dst, int n,
    const int* __restrict__ flagp)
{
  const int i = blockIdx.x * 256 + threadIdx.x;
  if (i >= n) return;
  if (flagp[0]) dst[i] = ((const unsigned short*)src)[i];
  else          dst[i] = f2b(((const float*)src)[i]);
}

__global__ __launch_bounds__(256) void k_cvt(
    const void* __restrict__ in, float* __restrict__ of,
    unsigned short* __restrict__ ob, const int* __restrict__ flagp)
{
  const size_t i = (size_t)blockIdx.x * 256 + threadIdx.x;
  if (flagp[0]) {
    const unsigned short u = ((const unsigned short*)in)[i];
    of[i] = b2f(u); ob[i] = u;
  } else {
    const float v = ((const float*)in)[i];
    of[i] = v; ob[i] = f2b(v);
  }
}

__global__ __launch_bounds__(256) void k_addin(
    const void* __restrict__ a, const void* __restrict__ b,
    unsigned short* __restrict__ c, const int* __restrict__ flagp)
{
  const size_t i = (size_t)blockIdx.x * 256 + threadIdx.x;
  float v;
  if (flagp[0]) v = b2f(((const unsigned short*)a)[i]) + b2f(((const unsigned short*)b)[i]);
  else          v = ((const float*)a)[i] + ((const float*)b)[i];
  c[i] = f2b(v);
}

// ---------------------------------------------------------------------------
// Generic MFMA GEMM: C[M,N] = act(A[M,K] @ W[N,K]^T + bias)  (as round 2)
// ---------------------------------------------------------------------------
__global__ __launch_bounds__(256) void k_gemm(
    const unsigned short* __restrict__ A, int lda,
    const unsigned short* __restrict__ W, int ldw,
    const unsigned short* __restrict__ bias,
    int N, int K, int act,
    float* __restrict__ outF,
    void* __restrict__ outBv, size_t oboff, int scatter, int sB, int sQ,
    const int* __restrict__ flagp, int dmode)
{
  __shared__ __align__(16) unsigned short As[64][40];
  __shared__ __align__(16) unsigned short Ws[64][40];
  const int m0 = blockIdx.y * 64;
  const int n0 = blockIdx.x * 64;
  const int tid = threadIdx.x;
  const int wid = tid >> 6, lane = tid & 63;
  const int srow = tid >> 2;          // 0..63
  const int scol = (tid & 3) << 3;    // 0,8,16,24
  const size_t arow = (size_t)(m0 + srow) * lda + scol;
  const bool wvalid = (n0 + srow) < N;
  const size_t wrow = (size_t)(n0 + srow) * ldw + scol;
  const int obf = (outBv && dmode) ? flagp[0] : 1;

  f4 acc[4];
#pragma unroll
  for (int j = 0; j < 4; ++j) acc[j] = (f4){0.f, 0.f, 0.f, 0.f};

  for (int k0 = 0; k0 < K; k0 += 32) {
    __syncthreads();
    *(uint4*)&As[srow][scol] = *(const uint4*)(A + arow + k0);
    uint4 wv = make_uint4(0u, 0u, 0u, 0u);
    if (wvalid) wv = *(const uint4*)(W + wrow + k0);
    *(uint4*)&Ws[srow][scol] = wv;
    __syncthreads();
    const int fr = lane & 15, fk = (lane >> 4) << 3;
    const bf8 af = *(const bf8*)&As[wid * 16 + fr][fk];
    const bf8 b0 = *(const bf8*)&Ws[ 0 + fr][fk];
    const bf8 b1 = *(const bf8*)&Ws[16 + fr][fk];
    const bf8 b2 = *(const bf8*)&Ws[32 + fr][fk];
    const bf8 b3 = *(const bf8*)&Ws[48 + fr][fk];
    acc[0] = __builtin_amdgcn_mfma_f32_16x16x32_bf16(af, b0, acc[0], 0, 0, 0);
    acc[1] = __builtin_amdgcn_mfma_f32_16x16x32_bf16(af, b1, acc[1], 0, 0, 0);
    acc[2] = __builtin_amdgcn_mfma_f32_16x16x32_bf16(af, b2, acc[2], 0, 0, 0);
    acc[3] = __builtin_amdgcn_mfma_f32_16x16x32_bf16(af, b3, acc[3], 0, 0, 0);
  }

  const int rbase = m0 + wid * 16 + ((lane >> 4) << 2);
  const int cbase = n0 + (lane & 15);
#pragma unroll
  for (int j = 0; j < 4; ++j) {
    const int col = cbase + j * 16;
    if (col < N) {
      const float bv = bias ? b2f(bias[col]) : 0.f;
#pragma unroll
      for (int r = 0; r < 4; ++r) {
        const int row = rbase + r;
        float v = acc[j][r] + bv;
        if (act == 1) v = fmaxf(v, 0.f);
        else if (act == 2) v = 1.f / (1.f + __expf(-v));
        if (outF) outF[(size_t)row * N + col] = v;
        if (outBv) {
          const size_t o = scatter
              ? ((size_t)(row & 63) * sB + (size_t)(row >> 6) * sQ + col)
              : ((size_t)row * N + col);
          if (obf) ((unsigned short*)outBv)[oboff + o] = f2b(v);
          else     ((float*)outBv)[oboff + o] = v;
        }
      }
    }
  }
}

// ---------------------------------------------------------------------------
// MFMA flash attention. Block = (b, h, 64-query tile), 4 waves; wave w owns
// query rows [w*16, w*16+16). Per 64-key tile: stage K row-major + V
// transposed in LDS, S = Q@K^T via 4 MFMAs (dh=32 = one K-step), online
// softmax (row state replicated across the 16 lanes of a row group), P->bf16
// via wave-private LDS strip, O += P@V via 4 MFMAs. fp32 accumulators.
// q/k/v: bf16 token-major ([token][ld*], token = seq*Bn + b, head at h*32).
// ---------------------------------------------------------------------------
__global__ __launch_bounds__(256) void k_fattn(
    const unsigned short* __restrict__ qb, int ldq,
    const unsigned short* __restrict__ kb, int ldk,
    const unsigned short* __restrict__ vb, int ldv,
    unsigned short* __restrict__ outp, int Lk)
{
  __shared__ __align__(16) unsigned short Qt[64][40];
  __shared__ __align__(16) unsigned short Kt[64][40];
  __shared__ __align__(16) unsigned short VT[32][72];   // [d][key] transposed
  __shared__ __align__(16) unsigned short Pst[4][16][72];

  const int b = blockIdx.x, h = blockIdx.y, qt = blockIdx.z;
  const int tid = threadIdx.x, w = tid >> 6, lane = tid & 63;
  const int q0 = qt * 64;
  const int fr = lane & 15, fk = (lane >> 4) << 3;

  // stage Q tile (zero-fill past Qn)
  {
    const int q = tid >> 2, d0 = (tid & 3) << 3;
    uint4 u = make_uint4(0u, 0u, 0u, 0u);
    if (q0 + q < Qn)
      u = *(const uint4*)(qb + (size_t)((q0 + q) * Bn + b) * ldq + h * DH + d0);
    *(uint4*)&Qt[q][d0] = u;
  }
  __syncthreads();
  const bf8 qf = *(const bf8*)&Qt[w * 16 + fr][fk];

  f4 oacc[2];
  oacc[0] = (f4){0.f, 0.f, 0.f, 0.f};
  oacc[1] = (f4){0.f, 0.f, 0.f, 0.f};
  float mrow[4], lrow[4];
#pragma unroll
  for (int r = 0; r < 4; ++r) { mrow[r] = -INFINITY; lrow[r] = 0.f; }

  const float scale = 0.17677669529663687f;  // 1/sqrt(32)
  const int KT = (Lk + 63) >> 6;

  for (int kt = 0; kt < KT; ++kt) {
    __syncthreads();
    {
      const int k = tid >> 2, d0 = (tid & 3) << 3;
      const bool valid = (kt * 64 + k) < Lk;
      uint4 uk = make_uint4(0u, 0u, 0u, 0u);
      uint4 uv = make_uint4(0u, 0u, 0u, 0u);
      if (valid) {
        const size_t roff = (size_t)((kt * 64 + k) * Bn + b);
        uk = *(const uint4*)(kb + roff * ldk + h * DH + d0);
        uv = *(const uint4*)(vb + roff * ldv + h * DH + d0);
      }
      *(uint4*)&Kt[k][d0] = uk;
      const unsigned short* us = (const unsigned short*)&uv;
#pragma unroll
      for (int j = 0; j < 8; ++j) VT[d0 + j][k] = us[j];
    }
    __syncthreads();

    // S = Q @ K^T  (16x64 strip per wave)
    f4 s[4];
#pragma unroll
    for (int f = 0; f < 4; ++f) {
      const bf8 kf = *(const bf8*)&Kt[f * 16 + fr][fk];
      s[f] = __builtin_amdgcn_mfma_f32_16x16x32_bf16(
          qf, kf, (f4){0.f, 0.f, 0.f, 0.f}, 0, 0, 0);
    }

    // online softmax per row r (row = (lane>>4)*4 + r within strip)
#pragma unroll
    for (int r = 0; r < 4; ++r) {
      float rm = -INFINITY;
#pragma unroll
      for (int f = 0; f < 4; ++f) {
        float v = s[f][r] * scale;
        const int col = kt * 64 + f * 16 + fr;
        if (col >= Lk) v = -1.0e30f;
        s[f][r] = v;
        rm = fmaxf(rm, v);
      }
#pragma unroll
      for (int off = 8; off >= 1; off >>= 1) rm = fmaxf(rm, __shfl_xor(rm, off));
      const float mnew = fmaxf(mrow[r], rm);
      const float corr = __expf(mrow[r] - mnew);   // first iter: exp(-inf)=0
      float rs = 0.f;
#pragma unroll
      for (int f = 0; f < 4; ++f) {
        const float p = __expf(s[f][r] - mnew);
        s[f][r] = p;
        rs += p;
      }
#pragma unroll
      for (int off = 8; off >= 1; off >>= 1) rs += __shfl_xor(rs, off);
      lrow[r] = lrow[r] * corr + rs;
      mrow[r] = mnew;
      oacc[0][r] *= corr;
      oacc[1][r] *= corr;
      const int row = ((lane >> 4) << 2) + r;
#pragma unroll
      for (int f = 0; f < 4; ++f) Pst[w][row][f * 16 + fr] = f2b(s[f][r]);
    }

    // O += P @ V   (P: wave strip 16x64, V^T: [d][key])
#pragma unroll
    for (int kk = 0; kk < 2; ++kk) {
      const bf8 pa = *(const bf8*)&Pst[w][fr][kk * 32 + fk];
#pragma unroll
      for (int f = 0; f < 2; ++f) {
        const bf8 vf = *(const bf8*)&VT[f * 16 + fr][kk * 32 + fk];
        oacc[f] = __builtin_amdgcn_mfma_f32_16x16x32_bf16(pa, vf, oacc[f], 0, 0, 0);
      }
    }
  }

  // epilogue: O /= l, store
#pragma unroll
  for (int f = 0; f < 2; ++f) {
#pragma unroll
    for (int r = 0; r < 4; ++r) {
      const int row = w * 16 + ((lane >> 4) << 2) + r;
      const int q = q0 + row;
      if (q < Qn)
        outp[(size_t)(q * Bn + b) * D + h * DH + f * 16 + fr] =
            f2b(oacc[f][r] / lrow[r]);
    }
  }
}

// ---------------------------------------------------------------------------
// Fused (x + res) -> LayerNorm (as round 2).
// ---------------------------------------------------------------------------
__global__ __launch_bounds__(256) void k_ln(
    const float* __restrict__ x, const float* __restrict__ res,
    const unsigned short* __restrict__ gs, const unsigned short* __restrict__ gb,
    float* __restrict__ outF, unsigned short* __restrict__ outB1,
    void* __restrict__ outB2v, size_t o2off, const int* __restrict__ flagp)
{
  const int wid = threadIdx.x >> 6, lane = threadIdx.x & 63;
  const size_t t = (size_t)blockIdx.x * 4 + wid;
  const int fl = outB2v ? flagp[0] : 1;
  const float* xp = x + t * D;
  float v[4];
#pragma unroll
  for (int j = 0; j < 4; ++j) {
    const int d = lane + j * 64;
    float u = xp[d];
    if (res) u += res[t * D + d];
    v[j] = u;
  }
  float s = v[0] + v[1] + v[2] + v[3];
  float ss = v[0]*v[0] + v[1]*v[1] + v[2]*v[2] + v[3]*v[3];
#pragma unroll
  for (int off = 32; off >= 1; off >>= 1) {
    s += __shfl_xor(s, off);
    ss += __shfl_xor(ss, off);
  }
  const float mean = s * (1.f / 256.f);
  const float var = ss * (1.f / 256.f) - mean * mean;
  const float rs = rsqrtf(var + 1e-5f);
#pragma unroll
  for (int j = 0; j < 4; ++j) {
    const int d = lane + j * 64;
    const float y = (v[j] - mean) * rs * b2f(gs[d]) + b2f(gb[d]);
    if (outF) outF[t * D + d] = y;
    if (outB1) outB1[t * D + d] = f2b(y);
    if (outB2v) {
      if (fl) ((unsigned short*)outB2v)[o2off + t * D + d] = f2b(y);
      else    ((float*)outB2v)[o2off + t * D + d] = y;
    }
  }
}

// -------------------------- elementwise helpers ----------------------------
__global__ __launch_bounds__(256) void k_addfb(
    const float* __restrict__ a, const unsigned short* __restrict__ b,
    unsigned short* __restrict__ c)
{
  const size_t i = (size_t)blockIdx.x * 256 + threadIdx.x;
  c[i] = f2b(a[i] + b2f(b[i]));
}
__global__ __launch_bounds__(256) void k_aug(
    const unsigned short* __restrict__ g, const unsigned short* __restrict__ sm,
    const unsigned short* __restrict__ it, float* __restrict__ of,
    unsigned short* __restrict__ ob)
{
  const size_t i = (size_t)blockIdx.x * 256 + threadIdx.x;
  const float v = b2f(g[i]) * b2f(sm[i]) + b2f(it[i]);
  of[i] = v;
  ob[i] = f2b(v);
}

// argmax over NOBJ=81 logits, first-max tie-break (matches np.argmax).
__global__ __launch_bounds__(256) void k_argmax(
    const float* __restrict__ logits, int* __restrict__ idx)
{
  const int wid = threadIdx.x >> 6, lane = threadIdx.x & 63;
  const size_t t = (size_t)blockIdx.x * 4 + wid;
  const float* p = logits + t * NOBJ;
  float bv = -INFINITY; int bi = 0;
  bv = p[lane < NOBJ ? lane : 0]; bi = lane < NOBJ ? lane : 0;
  if (lane >= NOBJ) { bv = p[0]; bi = 0; }
  if (lane + 64 < NOBJ) {
    const float v = p[lane + 64];
    if (v > bv) { bv = v; bi = lane + 64; }
  }
#pragma unroll
  for (int off = 32; off >= 1; off >>= 1) {
    const float ov = __shfl_xor(bv, off);
    const int oi = __shfl_xor(bi, off);
    if (ov > bv || (ov == bv && oi < bi)) { bv = ov; bi = oi; }
  }
  if (lane == 0) idx[t] = bi;
}

// cog[t][0..128) = co[idx[t]][0..117), zero-padded to K=128.
__global__ __launch_bounds__(256) void k_gather(
    const int* __restrict__ idx, const unsigned short* __restrict__ co,
    unsigned short* __restrict__ cog)
{
  const size_t n = (size_t)blockIdx.x * 256 + threadIdx.x;
  const int t = (int)(n >> 7), j = (int)(n & 127);
  cog[n] = (j < NVERB) ? co[(size_t)idx[t] * NVERB + j] : (unsigned short)0;
}

// -------------------------- semantic graph (tiny) --------------------------
__global__ __launch_bounds__(256) void k_semproj(
    const unsigned short* __restrict__ wemb, const unsigned short* __restrict__ sw,
    const unsigned short* __restrict__ sb, float* __restrict__ out)
{
  const int j = blockIdx.y;
  const int n = blockIdx.x * 256 + threadIdx.x;   // < 117*256
  const int mm = n >> 8, c = n & 255;
  const unsigned short* wr = sw + (size_t)(j * D + c) * WDIM;
  const unsigned short* xr = wemb + (size_t)mm * WDIM;
  float s = 0.f;
  for (int k = 0; k < WDIM; ++k) s += b2f(xr[k]) * b2f(wr[k]);
  out[(size_t)j * (NVERB * D) + n] = s + b2f(sb[j * D + c]);
}
__global__ __launch_bounds__(256) void k_semqk(
    const float* __restrict__ sq, const float* __restrict__ sk,
    float* __restrict__ sqk)
{
  const int n = blockIdx.x * 256 + threadIdx.x;
  if (n >= NVERB * NVERB) return;
  const int mm = n / NVERB, c = n - mm * NVERB;
  float s = 0.f;
  for (int k = 0; k < D; ++k) s += sq[mm * D + k] * sk[c * D + k];
  sqk[n] = s;
}
__global__ __launch_bounds__(256) void k_semfin(
    const float* __restrict__ sqk, const float* __restrict__ sv,
    const float* __restrict__ s3, unsigned short* __restrict__ semT)
{
  const int n = blockIdx.x * 256 + threadIdx.x;   // 256*128
  const int c = n >> 7, mm = n & 127;
  unsigned short r = 0;
  if (mm < NVERB) {
    float s = 0.f;
    for (int k = 0; k < NVERB; ++k) s += sqk[mm * NVERB + k] * sv[k * D + c];
    r = f2b(fmaxf(s, 0.f) + s3[mm * D + c]);
  }
  semT[c * 128 + mm] = r;
}

// ---------------------------------------------------------------------------
extern "C" void kernel_launch(void* const* d_in, const int* in_sizes, int n_in,
                              void* d_out, int out_size, void* d_ws, size_t ws_size,
                              hipStream_t stream)
{
  const void* tgt      = d_in[0];
  const void* mem      = d_in[1];
  const void* qpos     = d_in[2];
  const void* pos      = d_in[3];
  const void* sa_in_w  = d_in[4];
  const void* sa_in_b  = d_in[5];
  const void* sa_out_w = d_in[6];
  const void* sa_out_b = d_in[7];
  const void* ca_in_w  = d_in[8];
  const void* ca_in_b  = d_in[9];
  const void* ca_out_w = d_in[10];
  const void* ca_out_b = d_in[11];
  const void* ln_s     = d_in[12];
  const void* ln_b     = d_in[13];
  const void* ff1_w    = d_in[14];
  const void* ff1_b    = d_in[15];
  const void* ff2_w    = d_in[16];
  const void* ff2_b    = d_in[17];
  const void* sem_w    = d_in[18];
  const void* sem_b    = d_in[19];
  const void* gate_w   = d_in[20];
  const void* gate_b   = d_in[21];
  const void* vnorm_s  = d_in[22];
  const void* vnorm_b  = d_in[23];
  const void* fnorm_s  = d_in[24];
  const void* fnorm_b  = d_in[25];
  const void* obj_w    = d_in[26];
  const void* obj_b    = d_in[27];
  const void* verb_w   = d_in[28];
  const void* verb_b   = d_in[29];
  const void* wemb = d_in[30];
  const void* co   = d_in[31];
  if (in_sizes[30] == NOBJ * NVERB) { co = d_in[30]; wemb = d_in[31]; }
  (void)ws_size; (void)out_size; (void)n_in;

  // ----- workspace carving (deterministic; same every call) -----
  char* wp = (char*)d_ws;
  auto alloc = [&](size_t bytes) -> void* {
    void* p = (void*)wp;
    wp += (bytes + 255) & ~(size_t)255;
    return p;
  };
  int*   flagp   = (int*)alloc(256);
  float* out_f   = (float*)alloc((size_t)TQ * D * 4);
  float* x_f     = (float*)alloc((size_t)TQ * D * 4);
  float* t0_f    = (float*)alloc((size_t)TQ * D * 4);
  float* obj_f   = (float*)alloc((size_t)TQ * NOBJ * 4);
  int*   idx     = (int*)alloc((size_t)TQ * 4);
  unsigned short* out_bf   = (unsigned short*)alloc((size_t)TQ * D * 2);
  unsigned short* qk_bf    = (unsigned short*)alloc((size_t)TQ * D * 2);
  unsigned short* qk2_bf   = (unsigned short*)alloc((size_t)TQ * 512 * 2); // SA q|k; reused as CA q
  unsigned short* v_bf     = (unsigned short*)alloc((size_t)TQ * D * 2);
  unsigned short* attn_bf  = (unsigned short*)alloc((size_t)TQ * D * 2);
  unsigned short* x_bf     = (unsigned short*)alloc((size_t)TQ * D * 2);   // FF1 in; reused as vln
  unsigned short* inter_bf = (unsigned short*)alloc((size_t)TQ * D * 2);
  unsigned short* gate_bf  = (unsigned short*)alloc((size_t)TQ * D * 2);
  unsigned short* sem_bf   = (unsigned short*)alloc((size_t)TQ * D * 2);
  unsigned short* memq_bf  = (unsigned short*)alloc((size_t)TS * D * 2);
  unsigned short* mem_bf   = (unsigned short*)alloc((size_t)TS * D * 2);
  unsigned short* uni      = (unsigned short*)alloc((size_t)2 * TS * D * 2);
  unsigned short* kca_bf   = uni;
  unsigned short* vca_bf   = uni + (size_t)TS * D;
  unsigned short* ffh_bf   = uni;
  unsigned short* cog_bf   = (unsigned short*)alloc((size_t)TQ * 128 * 2);
  unsigned short* semT_bf  = (unsigned short*)alloc((size_t)D * 128 * 2);
  float* semp_f = (float*)alloc((size_t)4 * NVERB * D * 4);   // sq|sk|sv|s3
  float* sqk_f  = (float*)alloc((size_t)NVERB * NVERB * 4);
  unsigned short* qca_bf = qk2_bf;   // alias (SA qk dead before CA q write)
  unsigned short* vln_bf = x_bf;     // alias (FF1 consumed x_bf already)
  unsigned short* dout = (unsigned short*)d_out;

  // ----- dtype detect + input canonicalization -----
  k_detect<<<1, 1, 0, stream>>>(vnorm_s, flagp);
  auto cvt = [&](const void* src, size_t n) -> unsigned short* {
    unsigned short* dst = (unsigned short*)alloc(n * 2);
    k_cvtin<<<(unsigned)((n + 255) / 256), 256, 0, stream>>>(src, dst, (int)n, flagp);
    return dst;
  };
  unsigned short* qpos_b  = cvt(qpos, (size_t)TQ * D);
  unsigned short* saw_b   = cvt(sa_in_w, (size_t)Lnum * 768 * D);
  unsigned short* sab_b   = cvt(sa_in_b, (size_t)Lnum * 768);
  unsigned short* saow_b  = cvt(sa_out_w, (size_t)Lnum * D * D);
  unsigned short* saob_b  = cvt(sa_out_b, (size_t)Lnum * D);
  unsigned short* caw_b   = cvt(ca_in_w, (size_t)Lnum * 768 * D);
  unsigned short* cab_b   = cvt(ca_in_b, (size_t)Lnum * 768);
  unsigned short* caow_b  = cvt(ca_out_w, (size_t)Lnum * D * D);
  unsigned short* caob_b  = cvt(ca_out_b, (size_t)Lnum * D);
  unsigned short* lns_b   = cvt(ln_s, (size_t)Lnum * 3 * D);
  unsigned short* lnb_b   = cvt(ln_b, (size_t)Lnum * 3 * D);
  unsigned short* ff1w_b  = cvt(ff1_w, (size_t)Lnum * DFF * D);
  unsigned short* ff1b_b  = cvt(ff1_b, (size_t)Lnum * DFF);
  unsigned short* ff2w_b  = cvt(ff2_w, (size_t)Lnum * D * DFF);
  unsigned short* ff2b_b  = cvt(ff2_b, (size_t)Lnum * D);
  unsigned short* semw_b  = cvt(sem_w, (size_t)4 * D * WDIM);
  unsigned short* semb_b  = cvt(sem_b, (size_t)4 * D);
  unsigned short* gatew_b = cvt(gate_w, (size_t)D * D);
  unsigned short* gateb_b = cvt(gate_b, (size_t)D);
  unsigned short* vns_b   = cvt(vnorm_s, (size_t)D);
  unsigned short* vnb_b   = cvt(vnorm_b, (size_t)D);
  unsigned short* fns_b   = cvt(fnorm_s, (size_t)D);
  unsigned short* fnb_b   = cvt(fnorm_b, (size_t)D);
  unsigned short* objw_b  = cvt(obj_w, (size_t)NOBJ * D);
  unsigned short* objb_b  = cvt(obj_b, (size_t)NOBJ);
  unsigned short* verbw_b = cvt(verb_w, (size_t)NVERB * D);
  unsigned short* verbb_b = cvt(verb_b, (size_t)NVERB);
  unsigned short* co_b    = cvt(co, (size_t)NOBJ * NVERB);
  unsigned short* wemb_b  = cvt(wemb, (size_t)NVERB * WDIM);
  k_cvtin<<<(TS * D + 255) / 256, 256, 0, stream>>>(mem, mem_bf, TS * D, flagp);

  auto gemm = [&](const void* A, int lda, const void* W, int ldw,
                  const void* bias, int M, int N, int K, int act,
                  void* outF, void* outBv, size_t oboff, int scatter,
                  int sB, int sQ, int dmode) {
    dim3 grid((N + 63) / 64, M / 64);
    k_gemm<<<grid, dim3(256), 0, stream>>>(
        (const unsigned short*)A, lda, (const unsigned short*)W, ldw,
        (const unsigned short*)bias, N, K, act,
        (float*)outF, outBv, oboff, scatter, sB, sQ, flagp, dmode);
  };

  // ----- pre-loop -----
  k_cvt<<<TQ * D / 256, 256, 0, stream>>>(tgt, out_f, out_bf, flagp);
  k_addin<<<TS * D / 256, 256, 0, stream>>>(mem, pos, memq_bf, flagp);
  k_semproj<<<dim3(NVERB, 4), 256, 0, stream>>>(wemb_b, semw_b, semb_b, semp_f);
  k_semqk<<<(NVERB * NVERB + 255) / 256, 256, 0, stream>>>(
      semp_f, semp_f + NVERB * D, sqk_f);
  k_semfin<<<(D * 128) / 256, 256, 0, stream>>>(
      sqk_f, semp_f + 2 * NVERB * D, semp_f + 3 * NVERB * D, semT_bf);

  const dim3 attn_grid(Bn, NH, (Qn + 63) / 64);   // (64, 8, 5)

  for (int i = 0; i < Lnum; ++i) {
    const unsigned short* saw = saw_b + (size_t)i * 768 * D;
    const unsigned short* sab = sab_b + (size_t)i * 768;
    const unsigned short* caw = caw_b + (size_t)i * 768 * D;
    const unsigned short* cab = cab_b + (size_t)i * 768;

    // -------- self-attention --------
    k_addfb<<<TQ * D / 256, 256, 0, stream>>>(out_f, qpos_b, qk_bf);
    gemm(qk_bf, D, saw, D, sab, TQ, 512, D, 0, nullptr, qk2_bf, 0, 0, 0, 0, 0);
    gemm(out_bf, D, saw + (size_t)512 * D, D, sab + 512, TQ, D, D, 0,
         nullptr, v_bf, 0, 0, 0, 0, 0);
    k_fattn<<<attn_grid, 256, 0, stream>>>(qk2_bf, 512, qk2_bf + 256, 512,
                                           v_bf, D, attn_bf, Qn);
    gemm(attn_bf, D, saow_b + (size_t)i * D * D, D, saob_b + (size_t)i * D,
         TQ, D, D, 0, t0_f, nullptr, 0, 0, 0, 0, 0);
    k_ln<<<TQ / 4, 256, 0, stream>>>(out_f, t0_f, lns_b + (size_t)(i*3+0)*D,
                                     lnb_b + (size_t)(i*3+0)*D,
                                     x_f, (unsigned short*)nullptr,
                                     nullptr, 0, flagp);

    // -------- cross-attention --------
    k_addfb<<<TQ * D / 256, 256, 0, stream>>>(x_f, qpos_b, qk_bf);
    gemm(qk_bf, D, caw, D, cab, TQ, D, D, 0, nullptr, qca_bf, 0, 0, 0, 0, 0);
    gemm(memq_bf, D, caw + (size_t)256 * D, D, cab + 256, TS, D, D, 0,
         nullptr, kca_bf, 0, 0, 0, 0, 0);
    gemm(mem_bf, D, caw + (size_t)512 * D, D, cab + 512, TS, D, D, 0,
         nullptr, vca_bf, 0, 0, 0, 0, 0);
    k_fattn<<<attn_grid, 256, 0, stream>>>(qca_bf, D, kca_bf, D, vca_bf, D,
                                           attn_bf, Sn);
    gemm(attn_bf, D, caow_b + (size_t)i * D * D, D, caob_b + (size_t)i * D,
         TQ, D, D, 0, t0_f, nullptr, 0, 0, 0, 0, 0);
    k_ln<<<TQ / 4, 256, 0, stream>>>(x_f, t0_f, lns_b + (size_t)(i*3+1)*D,
                                     lnb_b + (size_t)(i*3+1)*D,
                                     x_f, x_bf, nullptr, 0, flagp);

    // -------- feed-forward --------
    gemm(x_bf, D, ff1w_b + (size_t)i * DFF * D, D, ff1b_b + (size_t)i * DFF,
         TQ, DFF, D, 1, nullptr, ffh_bf, 0, 0, 0, 0, 0);
    gemm(ffh_bf, DFF, ff2w_b + (size_t)i * D * DFF, DFF, ff2b_b + (size_t)i * D,
         TQ, D, DFF, 0, t0_f, nullptr, 0, 0, 0, 0, 0);
    k_ln<<<TQ / 4, 256, 0, stream>>>(x_f, t0_f, lns_b + (size_t)(i*3+2)*D,
                                     lnb_b + (size_t)(i*3+2)*D,
                                     out_f, (unsigned short*)nullptr,
                                     nullptr, 0, flagp);

    // -------- heads + semantic augmentation --------
    k_ln<<<TQ / 4, 256, 0, stream>>>(out_f, (const float*)nullptr, fns_b,
                                     fnb_b, (float*)nullptr, inter_bf,
                                     (i < 5) ? d_out : nullptr,
                                     IOFF + (size_t)i * TQ * D, flagp);
    gemm(inter_bf, D, objw_b, D, objb_b, TQ, NOBJ, D, 0, obj_f,
         d_out, OOFF + (size_t)i * Bn * Qn * NOBJ, 1, Qn * NOBJ, NOBJ, 1);
    k_argmax<<<TQ / 4, 256, 0, stream>>>(obj_f, idx);
    k_gather<<<TQ * 128 / 256, 256, 0, stream>>>(idx, co_b, cog_bf);
    gemm(cog_bf, 128, semT_bf, 128, nullptr, TQ, D, 128, 0, nullptr, sem_bf,
         0, 0, 0, 0, 0);
    gemm(inter_bf, D, gatew_b, D, gateb_b, TQ, D, D, 2, nullptr, gate_bf,
         0, 0, 0, 0, 0);
    k_aug<<<TQ * D / 256, 256, 0, stream>>>(gate_bf, sem_bf, inter_bf, out_f,
                                            out_bf);
    k_ln<<<TQ / 4, 256, 0, stream>>>(out_f, (const float*)nullptr, vns_b,
                                     vnb_b, (float*)nullptr, vln_bf,
                                     nullptr, 0, flagp);
    gemm(vln_bf, D, verbw_b, D, verbb_b, TQ, NVERB, D, 0, nullptr,
         d_out, VOFF + (size_t)i * Bn * Qn * NVERB, 1, Qn * NVERB, NVERB, 1);
  }

  // inters[-1] = LN(out_aug_5, fnorm)
  k_ln<<<TQ / 4, 256, 0, stream>>>(out_f, (const float*)nullptr, fns_b,
                                   fnb_b, (float*)nullptr,
                                   (unsigned short*)nullptr,
                                   d_out, IOFF + (size_t)5 * TQ * D, flagp);
  (void)dout;
}